// Round 2
// 524.529 us; speedup vs baseline: 1.0783x; 1.0783x over previous
//
#include <hip/hip_runtime.h>

// DCT-II 2D (ortho) = D @ X @ D^T per 1024x1024 image, 48 images.
// Both stages: Z = transpose(A @ D^T) via mfma operand swap.
// Stage 0: X fp32 -> bf16 (parked in d_out, free until stage-2 writes).
// GEMM: 256x256 tile, BK=64, 8 waves, 8-phase counted-vmcnt schedule
// (T2 st-16x32 LDS swizzle + T3/T4 counted vmcnt + T5 setprio + T1 XCD swizzle).
// v2 fix: drain vmcnt(0) after the K-loop — tail global_load_lds must not be
// in flight at s_endpgm (late LDS writes can corrupt a successor block's LDS).

typedef __bf16 bf16_t;
typedef __bf16 bf16x8 __attribute__((ext_vector_type(8)));
typedef float  f32x4  __attribute__((ext_vector_type(4)));

#define GLDS16(g, l) \
    __builtin_amdgcn_global_load_lds((__attribute__((address_space(1))) void*)(g), \
                                     (__attribute__((address_space(3))) void*)(l), 16, 0, 0)

#define FENCE() asm volatile("" ::: "memory")
#define BAR()   do { FENCE(); __builtin_amdgcn_s_barrier(); FENCE(); } while (0)
#define MFMA16(b, a, c) __builtin_amdgcn_mfma_f32_16x16x32_bf16((b), (a), (c), 0, 0, 0)

// ---- generate bf16 DCT matrix D[k][n] = s_k * cos(pi*(2n+1)*k/2048) ----
__global__ __launch_bounds__(256) void gen_dmat(bf16_t* __restrict__ D) {
    int idx = (blockIdx.x * 256 + threadIdx.x) * 4;
    int k = idx >> 10;
    int n0 = idx & 1023;
    float s = (k == 0) ? 0.03125f : 0.04419417382415922f;  // 1/32, sqrt(2)/32
#pragma unroll
    for (int j = 0; j < 4; ++j) {
        int n = n0 + j;
        int t = ((2 * n + 1) * k) & 4095;
        float ang = (float)t * 1.5339807878856412e-3f;      // pi/2048
        D[idx + j] = (bf16_t)(__cosf(ang) * s);
    }
}

// ---- X fp32 -> bf16, vectorized (32B in / 16B out per thread) ----
__global__ __launch_bounds__(256) void cvt_bf16(const float* __restrict__ X,
                                                bf16_t* __restrict__ Xb) {
    size_t i = ((size_t)blockIdx.x * 256 + threadIdx.x) * 8;
    const float4 a = *(const float4*)(X + i);
    const float4 b = *(const float4*)(X + i + 4);
    bf16x8 v;
    v[0] = (bf16_t)a.x; v[1] = (bf16_t)a.y; v[2] = (bf16_t)a.z; v[3] = (bf16_t)a.w;
    v[4] = (bf16_t)b.x; v[5] = (bf16_t)b.y; v[6] = (bf16_t)b.z; v[7] = (bf16_t)b.w;
    *(bf16x8*)(Xb + i) = v;
}

// ---- 256x256-tile 8-phase GEMM: Z = transpose(A @ D^T), A bf16 [1024][1024]/img
// LDS layout per matrix per buffer: 2 k-panels of [256 rows][32 elems] (64B rows).
// Swizzle: 16B chunk index ^= 2 when (row & 8) — applied to global SRC at staging
// (linear global_load_lds dest) and to ds_read addresses (both-sides, rule #21).
template <bool OUT_F32>
__global__ __launch_bounds__(512, 2) void dct_gemm8(const bf16_t* __restrict__ A,
                                                    const bf16_t* __restrict__ Dm,
                                                    void* __restrict__ Out) {
    __shared__ char smem[131072];   // A bufs: [0,64K)  B bufs: [64K,128K)

    const int tid  = threadIdx.x;
    const int lane = tid & 63;
    const int wv   = tid >> 6;          // 0..7
    const int l15  = lane & 15;
    const int quad = lane >> 4;
    const int wm   = (wv >> 2) * 128;   // 0 or 128
    const int wn   = (wv & 3) * 64;     // 0,64,128,192
    const int coff = (quad ^ ((l15 & 8) ? 2 : 0)) * 16;  // swizzled 16B chunk in 64B row

    // XCD-contiguous work decode: 768 blocks = 48 img x 16 tiles, 96 per XCD
    const int bid = blockIdx.x;
    const int swz = (bid & 7) * 96 + (bid >> 3);
    const int z   = swz >> 4;
    const int tt  = swz & 15;
    const int m0  = (tt & 3) * 256;
    const int n0  = (tt >> 2) * 256;

    const bf16_t* Ag = A  + (size_t)z * (1024 * 1024) + (size_t)m0 * 1024;
    const bf16_t* Bg = Dm + (size_t)n0 * 1024;

    const int sr  = tid >> 2;                    // staging row 0..127
    const int sc  = tid & 3;                     // 16B chunk within 64B row
    const int ssc = (sr & 8) ? (sc ^ 2) : sc;    // inverse-swizzled source chunk

    // stage half-tile h of K-tile tIdx (h: 0=A rows0-127, 1=A rows128-255, 2/3=B same)
    // buffer parity from REAL tIdx; source k clamped (uniform vmcnt counts, in-bounds)
    auto stage = [&](int tIdx, int h) {
        const int b  = tIdx & 1;
        const int kk = (tIdx < 16 ? tIdx : 15) * 64;
        const bf16_t* src = ((h < 2) ? Ag : Bg)
                          + (size_t)((h & 1) * 128 + sr) * 1024 + kk + ssc * 8;
        char* dst = smem + ((h < 2) ? 0 : 65536) + b * 32768
                  + (h & 1) * 8192 + sr * 64 + sc * 16;
        GLDS16(src, dst);               // k-panel 0
        GLDS16(src + 32, dst + 16384);  // k-panel 1
    };

    f32x4 acc[8][4];
#pragma unroll
    for (int i = 0; i < 8; ++i)
#pragma unroll
        for (int j = 0; j < 4; ++j) acc[i][j] = (f32x4){0.f, 0.f, 0.f, 0.f};

    // prologue: tile0 fully + tile1 half0; keep tile1.h0 in flight
    stage(0, 0); stage(0, 1); stage(0, 2); stage(0, 3);
    stage(1, 0);
    asm volatile("s_waitcnt vmcnt(2)" ::: "memory");
    BAR();

    bf16x8 afA[4][2], afB[4][2], bfA[2][2], bfB[2][2];

    for (int T = 0; T < 16; ++T) {
        const char* Ab = smem + (T & 1) * 32768;
        const char* Bb = smem + 65536 + (T & 1) * 32768;

        // ---- phase 1: read afA(8)+bfA(4); stage (T+1).h1; MFMA Q00 (i0-3 x j0-1)
#pragma unroll
        for (int i = 0; i < 4; ++i)
#pragma unroll
            for (int ks = 0; ks < 2; ++ks)
                afA[i][ks] = *(const bf16x8*)(Ab + ks * 16384 + (wm + i * 16 + l15) * 64 + coff);
#pragma unroll
        for (int j = 0; j < 2; ++j)
#pragma unroll
            for (int ks = 0; ks < 2; ++ks)
                bfA[j][ks] = *(const bf16x8*)(Bb + ks * 16384 + (wn + j * 16 + l15) * 64 + coff);
        stage(T + 1, 1);
        BAR();
        __builtin_amdgcn_s_setprio(1);
#pragma unroll
        for (int ks = 0; ks < 2; ++ks)
#pragma unroll
            for (int i = 0; i < 4; ++i)
#pragma unroll
                for (int j = 0; j < 2; ++j)
                    acc[i][j] = MFMA16(bfA[j][ks], afA[i][ks], acc[i][j]);
        __builtin_amdgcn_s_setprio(0);
        BAR();

        // ---- phase 2: read bfB(4); stage (T+1).h2; MFMA Q01 (i0-3 x j2-3)
#pragma unroll
        for (int j = 0; j < 2; ++j)
#pragma unroll
            for (int ks = 0; ks < 2; ++ks)
                bfB[j][ks] = *(const bf16x8*)(Bb + ks * 16384 + (wn + (j + 2) * 16 + l15) * 64 + coff);
        stage(T + 1, 2);
        BAR();
        __builtin_amdgcn_s_setprio(1);
#pragma unroll
        for (int ks = 0; ks < 2; ++ks)
#pragma unroll
            for (int i = 0; i < 4; ++i)
#pragma unroll
                for (int j = 0; j < 2; ++j)
                    acc[i][j + 2] = MFMA16(bfB[j][ks], afA[i][ks], acc[i][j + 2]);
        __builtin_amdgcn_s_setprio(0);
        BAR();

        // ---- phase 3: read afB(8); stage (T+1).h3; MFMA Q11 (i4-7 x j2-3)
        //      (last ds_reads of this buffer — drained before this phase's closing barrier)
#pragma unroll
        for (int i = 0; i < 4; ++i)
#pragma unroll
            for (int ks = 0; ks < 2; ++ks)
                afB[i][ks] = *(const bf16x8*)(Ab + ks * 16384 + (wm + (i + 4) * 16 + l15) * 64 + coff);
        stage(T + 1, 3);
        BAR();
        __builtin_amdgcn_s_setprio(1);
#pragma unroll
        for (int ks = 0; ks < 2; ++ks)
#pragma unroll
            for (int i = 0; i < 4; ++i)
#pragma unroll
                for (int j = 0; j < 2; ++j)
                    acc[i + 4][j + 2] = MFMA16(bfB[j][ks], afB[i][ks], acc[i + 4][j + 2]);
        __builtin_amdgcn_s_setprio(0);
        BAR();

        // ---- phase 4: stage (T+2).h0 (this buffer, reads done); counted vmcnt;
        //      MFMA Q10 (i4-7 x j0-1). vmcnt(2): everything older than (T+2).h0
        //      complete => all of tile T+1 staged; (T+2).h0 stays in flight.
        stage(T + 2, 0);
        asm volatile("s_waitcnt vmcnt(2)" ::: "memory");
        BAR();
        __builtin_amdgcn_s_setprio(1);
#pragma unroll
        for (int ks = 0; ks < 2; ++ks)
#pragma unroll
            for (int i = 0; i < 4; ++i)
#pragma unroll
                for (int j = 0; j < 2; ++j)
                    acc[i + 4][j] = MFMA16(bfA[j][ks], afB[i][ks], acc[i + 4][j]);
        __builtin_amdgcn_s_setprio(0);
        BAR();
    }

    // drain tail prefetches (tiles 16/17 clamped stages) BEFORE the workgroup can
    // exit — in-flight global_load_lds at s_endpgm may write a successor block's LDS.
    asm volatile("s_waitcnt vmcnt(0)" ::: "memory");

    // ---- epilogue: Z[n0+wn+j*16+quad*4+r][m0+wm+i*16+l15] = acc[i][j][r]
    const size_t boff = (size_t)z * (1024 * 1024);
    if constexpr (OUT_F32) {
        float* Og = (float*)Out + boff;
#pragma unroll
        for (int j = 0; j < 4; ++j) {
            int zr0 = n0 + wn + j * 16 + quad * 4;
#pragma unroll
            for (int r = 0; r < 4; ++r) {
                float* orow = Og + (size_t)(zr0 + r) * 1024 + m0 + wm + l15;
#pragma unroll
                for (int i = 0; i < 8; ++i)
                    orow[i * 16] = acc[i][j][r];
            }
        }
    } else {
        bf16_t* Og = (bf16_t*)Out + boff;
#pragma unroll
        for (int j = 0; j < 4; ++j) {
            int zr0 = n0 + wn + j * 16 + quad * 4;
#pragma unroll
            for (int r = 0; r < 4; ++r) {
                bf16_t* orow = Og + (size_t)(zr0 + r) * 1024 + m0 + wm + l15;
#pragma unroll
                for (int i = 0; i < 8; ++i)
                    orow[i * 16] = (bf16_t)acc[i][j][r];
            }
        }
    }
}

extern "C" void kernel_launch(void* const* d_in, const int* in_sizes, int n_in,
                              void* d_out, int out_size, void* d_ws, size_t ws_size,
                              hipStream_t stream) {
    (void)in_sizes; (void)n_in; (void)out_size; (void)ws_size;
    const float* X = (const float*)d_in[0];
    float* Y = (float*)d_out;

    // ws: [0,2MB) D bf16 ; [2MB, 2MB+96MB) V^T bf16.
    // Xb (bf16 copy of X, 96MB) lives in d_out — consumed by stage 1 before
    // stage 2 overwrites d_out with the final fp32 result.
    bf16_t* Dm = (bf16_t*)d_ws;
    bf16_t* Vt = (bf16_t*)((char*)d_ws + ((size_t)2 * 1024 * 1024));
    bf16_t* Xb = (bf16_t*)d_out;

    gen_dmat<<<1024, 256, 0, stream>>>(Dm);
    cvt_bf16<<<24576, 256, 0, stream>>>(X, Xb);

    dim3 grid(768), block(512);
    // stage 1: V^T = (Xb @ D^T)^T   (DCT along width, transposed store)
    dct_gemm8<false><<<grid, block, 0, stream>>>(Xb, Dm, (void*)Vt);
    // stage 2: Y = (V^T @ D^T)^T    (DCT along height, lands row-major)
    dct_gemm8<true><<<grid, block, 0, stream>>>(Vt, Dm, (void*)Y);
}